// Round 3
// baseline (483.618 us; speedup 1.0000x reference)
//
#include <hip/hip_runtime.h>

// Problem constants (from setup_inputs):
//   input_: (B=64, 2*N=16384, 2, 2, D1=16) f32
//   diag1/diag2: (N=8192, 2, 2, D2=8) f32
//   out: (B, N, 2, 2, DOUT=23) f32,  out[b,n,i,j,:] =
//        sum_k conv(x1[b,n,i,k,:], d1[n,k,j,:]) + sum_k conv(x2[b,n,i,k,:], d2[n,k,j,:])
//
// Round 3: one thread per (b, n, i). Sequential (half, k) segments keep live
// registers at ~acc(46) + x(16) + d(16); __launch_bounds__(256,4) caps VGPR
// at 128 -> 4 waves/SIMD (was 2 at VGPR=192, latency-bound at 26% HBM).
#define BB 64
#define NN 8192
#define D1C 16
#define D2C 8
#define DOUT 23

// One segment: fixed (half, k). xp -> 16 floats x[b,n,i,k,:],
// dp -> 16 floats d[n,k,j=0..1,v=0..7]. acc[j][u+v] += x[u]*d[j][v].
__device__ __forceinline__ void seg(const float4* __restrict__ xp,
                                    const float4* __restrict__ dp,
                                    float acc[2][DOUT]) {
    float4 xq0 = xp[0], xq1 = xp[1], xq2 = xp[2], xq3 = xp[3];
    float4 dq0 = dp[0], dq1 = dp[1], dq2 = dp[2], dq3 = dp[3];

    float xv[D1C] = {xq0.x, xq0.y, xq0.z, xq0.w, xq1.x, xq1.y, xq1.z, xq1.w,
                     xq2.x, xq2.y, xq2.z, xq2.w, xq3.x, xq3.y, xq3.z, xq3.w};
    float dd[2][D2C] = {{dq0.x, dq0.y, dq0.z, dq0.w, dq1.x, dq1.y, dq1.z, dq1.w},
                        {dq2.x, dq2.y, dq2.z, dq2.w, dq3.x, dq3.y, dq3.z, dq3.w}};

#pragma unroll
    for (int j = 0; j < 2; ++j) {
#pragma unroll
        for (int v = 0; v < D2C; ++v) {
            const float c = dd[j][v];
#pragma unroll
            for (int u = 0; u < D1C; ++u) {
                acc[j][u + v] += xv[u] * c;
            }
        }
    }
}

__global__ __launch_bounds__(256, 4) void hstackdiag_kernel(
    const float* __restrict__ input,
    const float* __restrict__ diag1,
    const float* __restrict__ diag2,
    float* __restrict__ out) {
    const int t = blockIdx.x * blockDim.x + threadIdx.x;  // linear (b, n, i)
    const int i = t & 1;
    const int n = (t >> 1) & (NN - 1);
    const int b = t >> 14;

    // x1[b][n][i][k][u]: float4 offset ((b*2N + n)*4 + i*2 + k)*4
    const float4* x1 = (const float4*)input +
                       ((size_t)b * (2 * NN) + n) * 16 + (size_t)i * 8;
    const float4* x2 = x1 + (size_t)NN * 16;
    // d[n][k][j][v]: float4 offset n*8 + k*4 (16 contiguous floats per k)
    const float4* d1 = (const float4*)diag1 + (size_t)n * 8;
    const float4* d2 = (const float4*)diag2 + (size_t)n * 8;

    float acc[2][DOUT];
#pragma unroll
    for (int j = 0; j < 2; ++j)
#pragma unroll
        for (int u = 0; u < DOUT; ++u) acc[j][u] = 0.0f;

    seg(x1 + 0, d1 + 0, acc);  // half 1, k=0
    seg(x1 + 4, d1 + 4, acc);  // half 1, k=1
    seg(x2 + 0, d2 + 0, acc);  // half 2, k=0
    seg(x2 + 4, d2 + 4, acc);  // half 2, k=1

    // Write 46 contiguous floats = 23 aligned float2 (byte offset t*184, %8==0).
    float2* o2 = (float2*)out + (size_t)t * DOUT;
    const float* a = &acc[0][0];
#pragma unroll
    for (int q = 0; q < DOUT; ++q) {
        o2[q] = make_float2(a[2 * q], a[2 * q + 1]);
    }
}

extern "C" void kernel_launch(void* const* d_in, const int* in_sizes, int n_in,
                              void* d_out, int out_size, void* d_ws, size_t ws_size,
                              hipStream_t stream) {
    const float* input = (const float*)d_in[0];
    const float* diag1 = (const float*)d_in[1];
    const float* diag2 = (const float*)d_in[2];
    float* out = (float*)d_out;

    const int total = BB * NN * 2;       // 1,048,576 threads, one per (b,n,i)
    const int block = 256;
    const int grid = total / block;      // 4096 blocks, exact
    hstackdiag_kernel<<<grid, block, 0, stream>>>(input, diag1, diag2, out);
}

// Round 4
// 171.906 us; speedup vs baseline: 2.8133x; 2.8133x over previous
//
#include <hip/hip_runtime.h>

// Problem constants (from setup_inputs):
//   input_: (B=64, 2*N=16384, 2, 2, D1=16) f32
//   diag1/diag2: (N=8192, 2, 2, D2=8) f32
//   out: (B, N, 2, 2, DOUT=23) f32,  out[b,n,i,j,:] =
//        sum_k conv(x1[b,n,i,k,:], d1[n,k,j,:]) + sum_k conv(x2[b,n,i,k,:], d2[n,k,j,:])
//
// Round 4: one thread per (b, n, i), sequential (half, k) segments.
// NO min-waves launch_bounds hint: round 3's (256,4) made the compiler pick
// VGPR=64 and spill the accumulator to scratch (FETCH 250->861 MB, 2x slower).
// Live set ~= acc(46) + x(16) + d(16) + addr -> expect ~100-140 VGPR, no spill.
#define BB 64
#define NN 8192
#define D1C 16
#define D2C 8
#define DOUT 23

// One segment: fixed (half, k). xp -> 16 floats x[b,n,i,k,:],
// dp -> 16 floats d[n,k,j=0..1,v=0..7]. acc[j][u+v] += x[u]*d[j][v].
__device__ __forceinline__ void seg(const float4* __restrict__ xp,
                                    const float4* __restrict__ dp,
                                    float acc[2][DOUT]) {
    float4 xq0 = xp[0], xq1 = xp[1], xq2 = xp[2], xq3 = xp[3];
    float4 dq0 = dp[0], dq1 = dp[1], dq2 = dp[2], dq3 = dp[3];

    float xv[D1C] = {xq0.x, xq0.y, xq0.z, xq0.w, xq1.x, xq1.y, xq1.z, xq1.w,
                     xq2.x, xq2.y, xq2.z, xq2.w, xq3.x, xq3.y, xq3.z, xq3.w};
    float dd[2][D2C] = {{dq0.x, dq0.y, dq0.z, dq0.w, dq1.x, dq1.y, dq1.z, dq1.w},
                        {dq2.x, dq2.y, dq2.z, dq2.w, dq3.x, dq3.y, dq3.z, dq3.w}};

#pragma unroll
    for (int j = 0; j < 2; ++j) {
#pragma unroll
        for (int v = 0; v < D2C; ++v) {
            const float c = dd[j][v];
#pragma unroll
            for (int u = 0; u < D1C; ++u) {
                acc[j][u + v] += xv[u] * c;
            }
        }
    }
}

__global__ __launch_bounds__(256) void hstackdiag_kernel(
    const float* __restrict__ input,
    const float* __restrict__ diag1,
    const float* __restrict__ diag2,
    float* __restrict__ out) {
    const int t = blockIdx.x * blockDim.x + threadIdx.x;  // linear (b, n, i)
    const int i = t & 1;
    const int n = (t >> 1) & (NN - 1);
    const int b = t >> 14;

    // x1[b][n][i][k][u]: float4 offset ((b*2N + n)*4 + i*2 + k)*4
    const float4* x1 = (const float4*)input +
                       ((size_t)b * (2 * NN) + n) * 16 + (size_t)i * 8;
    const float4* x2 = x1 + (size_t)NN * 16;
    // d[n][k][j][v]: float4 offset n*8 + k*4 (16 contiguous floats per k)
    const float4* d1 = (const float4*)diag1 + (size_t)n * 8;
    const float4* d2 = (const float4*)diag2 + (size_t)n * 8;

    float acc[2][DOUT];
#pragma unroll
    for (int j = 0; j < 2; ++j)
#pragma unroll
        for (int u = 0; u < DOUT; ++u) acc[j][u] = 0.0f;

    seg(x1 + 0, d1 + 0, acc);  // half 1, k=0
    seg(x1 + 4, d1 + 4, acc);  // half 1, k=1
    seg(x2 + 0, d2 + 0, acc);  // half 2, k=0
    seg(x2 + 4, d2 + 4, acc);  // half 2, k=1

    // Write 46 contiguous floats = 23 aligned float2 (byte offset t*184, %8==0).
    float2* o2 = (float2*)out + (size_t)t * DOUT;
    const float* a = &acc[0][0];
#pragma unroll
    for (int q = 0; q < DOUT; ++q) {
        o2[q] = make_float2(a[2 * q], a[2 * q + 1]);
    }
}

extern "C" void kernel_launch(void* const* d_in, const int* in_sizes, int n_in,
                              void* d_out, int out_size, void* d_ws, size_t ws_size,
                              hipStream_t stream) {
    const float* input = (const float*)d_in[0];
    const float* diag1 = (const float*)d_in[1];
    const float* diag2 = (const float*)d_in[2];
    float* out = (float*)d_out;

    const int total = BB * NN * 2;       // 1,048,576 threads, one per (b,n,i)
    const int block = 256;
    const int grid = total / block;      // 4096 blocks, exact
    hstackdiag_kernel<<<grid, block, 0, stream>>>(input, diag1, diag2, out);
}